// Round 5
// baseline (2289.564 us; speedup 1.0000x reference)
//
#include <hip/hip_runtime.h>
#include <cmath>

// Memory_76957224010242: 100-step Adam inference loop.
// G = W^T W, u = (x-c)@W once; per-iter s = r@G fused with Adam + loss.
// R5: loop GEMM gets 3-buffer 2-deep pipeline with counted vmcnt(3) + raw
// s_barrier (T3/T4) so cross-XCD rbf/G load latency hides under 2 K-steps of
// MFMA instead of draining vmcnt(0) every step.

#define B_SZ 512
#define H_SZ 2048
#define D_SZ 4096
#define ITERS 100

typedef __attribute__((ext_vector_type(8))) short short8;
typedef __attribute__((ext_vector_type(4))) float f32x4;

__device__ __forceinline__ unsigned short f2bf(float f) {
    unsigned u = __float_as_uint(f);
    u = (u + 0x7fffu + ((u >> 16) & 1u)) >> 16;  // RNE
    return (unsigned short)u;
}
__device__ __forceinline__ float bflo(unsigned mv) { return __uint_as_float(mv << 16); }
__device__ __forceinline__ float bfhi(unsigned mv) { return __uint_as_float(mv & 0xffff0000u); }

__device__ __forceinline__ void gload_lds16(const unsigned short* g, unsigned short* l) {
    __builtin_amdgcn_global_load_lds((const __attribute__((address_space(1))) void*)g,
                                     (__attribute__((address_space(3))) void*)l, 16, 0, 0);
}

// ---- W (D,H) f32 -> Wt (H,D) bf16 (transpose + cast) ----
__global__ __launch_bounds__(256) void k_transpose(const float* __restrict__ W,
                                                   unsigned short* __restrict__ Wt) {
    __shared__ unsigned short tile[64][72];
    const int d0 = blockIdx.x * 64, h0 = blockIdx.y * 64;
    const int t = threadIdx.x;
    const int lr = t >> 6, lc = t & 63;
#pragma unroll
    for (int rr = 0; rr < 16; ++rr) {
        const int dl = rr * 4 + lr;
        tile[dl][lc] = f2bf(W[(size_t)(d0 + dl) * H_SZ + h0 + lc]);
    }
    __syncthreads();
#pragma unroll
    for (int rr = 0; rr < 16; ++rr) {
        const int hl = rr * 4 + lr;
        Wt[(size_t)(h0 + hl) * D_SZ + d0 + lc] = tile[lc][hl];
    }
}

// ---- xc = (x - c) bf16, xc2[b] = sum_d (x-c)^2 ----
__global__ __launch_bounds__(256) void k_prepx(const float* __restrict__ x, const float* __restrict__ c,
                                               unsigned short* __restrict__ xcbf, float* __restrict__ xc2) {
    const int b = blockIdx.x, t = threadIdx.x;
    const float* xr = x + (size_t)b * D_SZ;
    unsigned short* orow = xcbf + (size_t)b * D_SZ;
    float acc = 0.f;
#pragma unroll
    for (int ch = 0; ch < 2; ++ch) {
        const int base = (ch * 256 + t) * 8;
        const float4 v0 = *(const float4*)(xr + base);
        const float4 v1 = *(const float4*)(xr + base + 4);
        const float4 c0 = *(const float4*)(c + base);
        const float4 c1 = *(const float4*)(c + base + 4);
        const float e0 = v0.x - c0.x, e1 = v0.y - c0.y, e2 = v0.z - c0.z, e3 = v0.w - c0.w;
        const float e4 = v1.x - c1.x, e5 = v1.y - c1.y, e6 = v1.z - c1.z, e7 = v1.w - c1.w;
        acc += e0 * e0 + e1 * e1 + e2 * e2 + e3 * e3 + e4 * e4 + e5 * e5 + e6 * e6 + e7 * e7;
        short8 ov;
        ov[0] = (short)f2bf(e0); ov[1] = (short)f2bf(e1); ov[2] = (short)f2bf(e2); ov[3] = (short)f2bf(e3);
        ov[4] = (short)f2bf(e4); ov[5] = (short)f2bf(e5); ov[6] = (short)f2bf(e6); ov[7] = (short)f2bf(e7);
        *(short8*)(orow + base) = ov;
    }
#pragma unroll
    for (int off = 32; off > 0; off >>= 1) acc += __shfl_down(acc, off);
    __shared__ float wred[4];
    if ((t & 63) == 0) wred[t >> 6] = acc;
    __syncthreads();
    if (t == 0) xc2[b] = wred[0] + wred[1] + wred[2] + wred[3];
}

// ---- r = r0; mv = 0; rbf0 = bf16(r0) ----
__global__ __launch_bounds__(256) void k_init(const float* __restrict__ r0, float* __restrict__ r,
                                              unsigned* __restrict__ mv,
                                              unsigned short* __restrict__ rbf0) {
    const size_t i = (size_t)blockIdx.x * 256 + threadIdx.x;
#pragma unroll
    for (int k = 0; k < 4; ++k) {
        const size_t idx = i + (size_t)k * 262144;
        const float val = r0[idx];
        r[idx] = val; mv[idx] = 0u; rbf0[idx] = f2bf(val);
    }
}

// ---- one-time TM x 64 tile bf16 MFMA GEMM (EPI 0: bf16 store; EPI 1: f32 store) ----
template <int TM, int EPI>
__global__ __launch_bounds__(256) void gemm64(
        const unsigned short* __restrict__ A, int lda,
        const unsigned short* __restrict__ Bt, int ldb, int K,
        unsigned short* __restrict__ Cb, float* __restrict__ Cf, int ldc) {
    __shared__ alignas(16) unsigned short Al[2][TM * 64];
    __shared__ alignas(16) unsigned short Bl[2][64 * 64];
    const int t = threadIdx.x, w = t >> 6, lane = t & 63;
    const int m0 = blockIdx.y * TM, n0 = blockIdx.x * 64;
    constexpr int NJ = (TM == 64) ? 2 : 1;
    const int row_base = (TM == 64) ? (w >> 1) * 32 : 0;
    const int col_base = (TM == 64) ? (w & 1) * 32 : w * 16;

    f32x4 acc[2][NJ] = {};

    auto stage = [&](int buf, int k0) {
#pragma unroll
        for (int h = 0; h < 2; ++h) {
            const int c = h * 256 + t;
            const int row = c >> 3, g = c & 7;
            const int gl = g ^ (row & 7);
            gload_lds16(Bt + (size_t)(n0 + row) * ldb + k0 + gl * 8, &Bl[buf][(h * 256 + w * 64) * 8]);
        }
        if constexpr (TM == 64) {
#pragma unroll
            for (int h = 0; h < 2; ++h) {
                const int c = h * 256 + t;
                const int row = c >> 3, g = c & 7;
                const int gl = g ^ (row & 7);
                gload_lds16(A + (size_t)(m0 + row) * lda + k0 + gl * 8, &Al[buf][(h * 256 + w * 64) * 8]);
            }
        } else {
            const int row = t >> 3, g = t & 7;
            const int gl = g ^ (row & 7);
            gload_lds16(A + (size_t)(m0 + row) * lda + k0 + gl * 8, &Al[buf][(w * 64) * 8]);
        }
    };

    stage(0, 0);
    const int nK = K >> 6;
    for (int kt = 0; kt < nK; ++kt) {
        __syncthreads();
        const int cur = kt & 1;
        if (kt + 1 < nK) stage(cur ^ 1, (kt + 1) << 6);
        const unsigned short* a_base = Al[cur];
        const unsigned short* b_base = Bl[cur];
#pragma unroll
        for (int kh = 0; kh < 2; ++kh) {
            short8 av[2], bv[NJ];
#pragma unroll
            for (int i = 0; i < 2; ++i) {
                const int row = row_base + i * 16 + (lane & 15);
                const int g = (kh * 4 + (lane >> 4)) ^ (row & 7);
                av[i] = *(const short8*)(a_base + row * 64 + g * 8);
            }
#pragma unroll
            for (int j = 0; j < NJ; ++j) {
                const int row = col_base + j * 16 + (lane & 15);
                const int g = (kh * 4 + (lane >> 4)) ^ (row & 7);
                bv[j] = *(const short8*)(b_base + row * 64 + g * 8);
            }
#pragma unroll
            for (int i = 0; i < 2; ++i)
#pragma unroll
                for (int j = 0; j < NJ; ++j)
                    acc[i][j] = __builtin_amdgcn_mfma_f32_16x16x32_bf16(av[i], bv[j], acc[i][j], 0, 0, 0);
        }
    }

#pragma unroll
    for (int i = 0; i < 2; ++i)
#pragma unroll
        for (int j = 0; j < NJ; ++j) {
            const int col = n0 + col_base + j * 16 + (lane & 15);
            const int row0 = m0 + row_base + i * 16 + ((lane >> 4) << 2);
#pragma unroll
            for (int q = 0; q < 4; ++q) {
                if constexpr (EPI == 0) Cb[(size_t)(row0 + q) * ldc + col] = f2bf(acc[i][j][q]);
                else Cf[(size_t)(row0 + q) * ldc + col] = acc[i][j][q];
            }
        }
}

// ---- loop kernel: s = r@G (M=512,N=2048,K=2048), fused Adam + loss.
// 32x64 tile, 512 blocks. 3 LDS buffers, 2-deep prefetch, counted vmcnt.
__global__ __launch_bounds__(256) void gemm_loop(
        const unsigned short* __restrict__ A,   // rbf in (B_SZ x H)
        const unsigned short* __restrict__ G,   // Gbf (H x H)
        float* __restrict__ rbuf, unsigned* __restrict__ mvbuf,
        const float* __restrict__ ubuf, const float* __restrict__ bvec,
        unsigned short* __restrict__ rbf_out, float* __restrict__ lossRow,
        float inv1, float inv2) {
    __shared__ alignas(16) unsigned short Al[3][32 * 64];
    __shared__ alignas(16) unsigned short Bl[3][64 * 64];
    const int t = threadIdx.x, w = t >> 6, lane = t & 63;
    const int m0 = blockIdx.y * 32, n0 = blockIdx.x * 64;
    const int col_base = w * 16;

    f32x4 acc[2] = {};

    // Epilogue-state prefetch FIRST: these are the oldest vmcnt entries, so the
    // kt=0 vmcnt(3) wait covers them once and the K-loop hides nothing extra.
    const int col = n0 + col_base + (lane & 15);
    float pre_r[8], pre_u[8];
    unsigned pre_mv[8];
    const float pre_b = bvec[col];
#pragma unroll
    for (int i = 0; i < 2; ++i) {
        const int row0 = m0 + i * 16 + ((lane >> 4) << 2);
#pragma unroll
        for (int q = 0; q < 4; ++q) {
            const size_t idx = (size_t)(row0 + q) * H_SZ + col;
            const int e = i * 4 + q;
            pre_r[e] = rbuf[idx];
            pre_u[e] = ubuf[idx];
            pre_mv[e] = mvbuf[idx];
        }
    }

    // 3 global_load_lds per thread per stage (2 B + 1 A) -> vmcnt counts in 3s.
    auto stage = [&](int buf, int k0) {
#pragma unroll
        for (int h = 0; h < 2; ++h) {
            const int c = h * 256 + t;
            const int row = c >> 3, g = c & 7;
            const int gl = g ^ (row & 7);
            gload_lds16(G + (size_t)(n0 + row) * H_SZ + k0 + gl * 8, &Bl[buf][(h * 256 + w * 64) * 8]);
        }
        const int row = t >> 3, g = t & 7;
        const int gl = g ^ (row & 7);
        gload_lds16(A + (size_t)(m0 + row) * H_SZ + k0 + gl * 8, &Al[buf][(w * 64) * 8]);
    };

    stage(0, 0);
    stage(1, 64);
    constexpr int nK = H_SZ / 64;  // 32
    for (int kt = 0; kt < nK; ++kt) {
        // Counted wait: stage kt's 3 loads are done when <=3 remain (stage kt+1
        // may stay in flight). Final step drains fully.
        if (kt < nK - 1) asm volatile("s_waitcnt vmcnt(3)" ::: "memory");
        else             asm volatile("s_waitcnt vmcnt(0)" ::: "memory");
        __builtin_amdgcn_s_barrier();
        __builtin_amdgcn_sched_barrier(0);  // pin ds_reads below the barrier
        if (kt + 2 < nK) stage((kt + 2) % 3, (kt + 2) * 64);
        const unsigned short* a_base = Al[kt % 3];
        const unsigned short* b_base = Bl[kt % 3];
#pragma unroll
        for (int kh = 0; kh < 2; ++kh) {
            short8 av[2], bv;
#pragma unroll
            for (int i = 0; i < 2; ++i) {
                const int row = i * 16 + (lane & 15);
                const int g = (kh * 4 + (lane >> 4)) ^ (row & 7);
                av[i] = *(const short8*)(a_base + row * 64 + g * 8);
            }
            {
                const int row = col_base + (lane & 15);
                const int g = (kh * 4 + (lane >> 4)) ^ (row & 7);
                bv = *(const short8*)(b_base + row * 64 + g * 8);
            }
#pragma unroll
            for (int i = 0; i < 2; ++i)
                acc[i] = __builtin_amdgcn_mfma_f32_16x16x32_bf16(av[i], bv, acc[i], 0, 0, 0);
        }
    }

    float lpart = 0.f;
#pragma unroll
    for (int i = 0; i < 2; ++i) {
        const int row0 = m0 + i * 16 + ((lane >> 4) << 2);
#pragma unroll
        for (int q = 0; q < 4; ++q) {
            const size_t idx = (size_t)(row0 + q) * H_SZ + col;
            const int e = i * 4 + q;
            const float s = acc[i][q];
            const float rold = pre_r[e];
            const float ue = pre_u[e];
            const float g = (2.0f / B_SZ) * (rold - pre_b - ue + s);
            lpart += (rold - pre_b) * (rold - pre_b) + rold * (s - 2.0f * ue);
            const float m1 = 0.9f * bflo(pre_mv[e]) + 0.1f * g;
            const float v1 = 0.999f * bfhi(pre_mv[e]) + 0.001f * (g * g);
            mvbuf[idx] = (unsigned)f2bf(m1) | ((unsigned)f2bf(v1) << 16);
            const float rn = rold - 0.01f * (m1 * inv1) / (sqrtf(v1 * inv2) + 1e-8f);
            rbuf[idx] = rn;
            rbf_out[idx] = f2bf(rn);
        }
    }
#pragma unroll
    for (int off = 32; off > 0; off >>= 1) lpart += __shfl_down(lpart, off);
    __shared__ float wred[4];
    if (lane == 0) wred[w] = lpart;
    __syncthreads();
    if (t == 0) lossRow[blockIdx.y * gridDim.x + blockIdx.x] = wred[0] + wred[1] + wred[2] + wred[3];
}

// ---- losses[t] = (sum_blocks lossPart + sum_b xc2) / B ----  (512 partials/iter)
__global__ __launch_bounds__(256) void k_finalize(const float* __restrict__ lossPart,
                                                  const float* __restrict__ xc2, float* __restrict__ out) {
    const int it = blockIdx.x, t = threadIdx.x;
    float p = lossPart[it * 512 + t] + lossPart[it * 512 + 256 + t] + xc2[t] + xc2[t + 256];
#pragma unroll
    for (int off = 32; off > 0; off >>= 1) p += __shfl_down(p, off);
    __shared__ float wred[4];
    if ((t & 63) == 0) wred[t >> 6] = p;
    __syncthreads();
    if (t == 0) out[(size_t)B_SZ * H_SZ + it] = (wred[0] + wred[1] + wred[2] + wred[3]) * (1.0f / B_SZ);
}

__global__ __launch_bounds__(256) void k_copy(const float* __restrict__ r, float* __restrict__ out) {
    const size_t i = ((size_t)blockIdx.x * 256 + threadIdx.x) * 4;
    *(float4*)(out + i) = *(const float4*)(r + i);
}

extern "C" void kernel_launch(void* const* d_in, const int* in_sizes, int n_in,
                              void* d_out, int out_size, void* d_ws, size_t ws_size,
                              hipStream_t stream) {
    const float* x = (const float*)d_in[0];
    const float* W = (const float*)d_in[1];
    const float* cvec = (const float*)d_in[2];
    const float* bvec = (const float*)d_in[3];
    const float* r0 = (const float*)d_in[4];
    float* out = (float*)d_out;
    char* ws = (char*)d_ws;

    unsigned short* Wt = (unsigned short*)(ws);              // 16 MB   (H x D bf16)
    unsigned short* Gbf = (unsigned short*)(ws + 16777216);  // 8 MB    (H x H bf16)
    unsigned short* xcbf = (unsigned short*)(ws + 25165824); // 4 MB    (B x D bf16)
    float* u = (float*)(ws + 29360128);                      // 4 MB    (B x H f32)
    float* r = (float*)(ws + 33554432);                      // 4 MB
    unsigned* mv = (unsigned*)(ws + 37748736);               // 4 MB    (bf16 m | bf16 v packed)
    unsigned short* rbf0 = (unsigned short*)(ws + 41943040); // 2 MB
    unsigned short* rbf1 = (unsigned short*)(ws + 44040192); // 2 MB
    float* xc2 = (float*)(ws + 46137344);                    // 2 KB
    float* lossPart = (float*)(ws + 46139392);               // 200 KB  (ITERS x 512)

    k_transpose<<<dim3(64, 32), 256, 0, stream>>>(W, Wt);
    k_prepx<<<512, 256, 0, stream>>>(x, cvec, xcbf, xc2);
    k_init<<<1024, 256, 0, stream>>>(r0, r, mv, rbf0);
    // G = Wt @ Wt^T (W^T W), M=N=2048, K=4096 (1024 blocks, 4/CU)
    gemm64<64, 0><<<dim3(32, 32), 256, 0, stream>>>(Wt, D_SZ, Wt, D_SZ, D_SZ, Gbf, nullptr, H_SZ);
    // u = (x-c) @ W, M=512, N=2048, K=4096 (512 blocks, 2/CU)
    gemm64<32, 1><<<dim3(32, 16), 256, 0, stream>>>(xcbf, D_SZ, Wt, D_SZ, D_SZ, nullptr, u, H_SZ);
    for (int it = 0; it < ITERS; ++it) {
        const float inv1 = (float)(1.0 / (1.0 - std::pow(0.9, (double)(it + 1))));
        const float inv2 = (float)(1.0 / (1.0 - std::pow(0.999, (double)(it + 1))));
        const unsigned short* rin = (it & 1) ? rbf1 : rbf0;
        unsigned short* rout = (it & 1) ? rbf0 : rbf1;
        gemm_loop<<<dim3(32, 16), 256, 0, stream>>>(rin, Gbf, r, mv, u, bvec, rout,
                                                    lossPart + (size_t)it * 512, inv1, inv2);
    }
    k_finalize<<<ITERS, 256, 0, stream>>>(lossPart, xc2, out);
    k_copy<<<1024, 256, 0, stream>>>(r, out);
}